// Round 1
// baseline (938.927 us; speedup 1.0000x reference)
//
#include <hip/hip_runtime.h>
#include <hip/hip_bf16.h>
#include <stdint.h>

#define NT 2048      // tokens = B*S
#define DD 1024      // hidden dim
#define FF 4096      // ffn dim
#define NE 8         // experts
#define NSLOT (NT*2) // top-2 slots

typedef float  f32x4  __attribute__((ext_vector_type(4)));
typedef __bf16 bf16x8 __attribute__((ext_vector_type(8)));
typedef __bf16 bf16x4 __attribute__((ext_vector_type(4)));

// ---------------- x fp32 -> bf16 ----------------
__global__ void k_convert_x(const float* __restrict__ x, __bf16* __restrict__ xb) {
    int i = blockIdx.x * blockDim.x + threadIdx.x;   // one float4 each
    float4 v = reinterpret_cast<const float4*>(x)[i];
    bf16x4 o;
    o[0] = (__bf16)v.x; o[1] = (__bf16)v.y; o[2] = (__bf16)v.z; o[3] = (__bf16)v.w;
    reinterpret_cast<bf16x4*>(xb)[i] = o;
}

// ---------------- router: logits, softmax, top-2, renorm ----------------
__global__ void k_router(const float* __restrict__ x, const float* __restrict__ rw,
                         const float* __restrict__ escale,
                         int* __restrict__ counts, int* __restrict__ rank,
                         int* __restrict__ tidx, float* __restrict__ tw) {
    int t = blockIdx.x;
    int lane = threadIdx.x;               // 64 lanes, one wave per token
    const float* xr = x + (size_t)t * DD + lane * 16;
    float acc[NE];
    #pragma unroll
    for (int e = 0; e < NE; e++) acc[e] = 0.f;
    #pragma unroll
    for (int c = 0; c < 4; c++) {
        float4 xv = reinterpret_cast<const float4*>(xr)[c];
        #pragma unroll
        for (int e = 0; e < NE; e++) {
            float4 rv = reinterpret_cast<const float4*>(rw + (size_t)e * DD + lane * 16)[c];
            acc[e] += xv.x*rv.x + xv.y*rv.y + xv.z*rv.z + xv.w*rv.w;
        }
    }
    #pragma unroll
    for (int e = 0; e < NE; e++) {
        #pragma unroll
        for (int off = 32; off > 0; off >>= 1) acc[e] += __shfl_xor(acc[e], off);
    }
    if (lane == 0) {
        int e0 = 0; float l0 = acc[0];
        #pragma unroll
        for (int e = 1; e < NE; e++) if (acc[e] > l0) { l0 = acc[e]; e0 = e; }
        int e1 = (e0 == 0) ? 1 : 0; float l1 = acc[e1];
        #pragma unroll
        for (int e = 0; e < NE; e++) if (e != e0 && acc[e] > l1) { l1 = acc[e]; e1 = e; }
        // full softmax over 8 logits (matches reference ordering exactly)
        float sum = 0.f;
        #pragma unroll
        for (int e = 0; e < NE; e++) sum += __expf(acc[e] - l0);
        float p0 = 1.0f / sum;                 // prob of best
        float p1 = __expf(l1 - l0) / sum;      // prob of 2nd
        // reference renormalizes by softmax over the PROB VALUES
        float z  = __expf(p1 - p0);
        float w0 = 1.0f / (1.0f + z);
        float w1 = 1.0f - w0;
        tidx[t*2+0] = e0; tw[t*2+0] = w0 * escale[e0];
        tidx[t*2+1] = e1; tw[t*2+1] = w1 * escale[e1];
        rank[t*2+0] = atomicAdd(&counts[e0], 1);
        rank[t*2+1] = atomicAdd(&counts[e1], 1);
    }
}

__global__ void k_prefix(const int* __restrict__ counts, int* __restrict__ offsets) {
    if (threadIdx.x == 0) {
        int s = 0;
        for (int e = 0; e < NE; e++) { offsets[e] = s; s += counts[e]; }
        offsets[NE] = s;
    }
}

__global__ void k_scatter(const int* __restrict__ tidx, const float* __restrict__ tw,
                          const int* __restrict__ rank, const int* __restrict__ offsets,
                          int* __restrict__ slot_token, int* __restrict__ slot_k,
                          float* __restrict__ slot_w) {
    int t = blockIdx.x * blockDim.x + threadIdx.x;
    if (t >= NT) return;
    #pragma unroll
    for (int k = 0; k < 2; k++) {
        int e = tidx[t*2+k];
        int p = offsets[e] + rank[t*2+k];
        slot_token[p] = t; slot_k[p] = k; slot_w[p] = tw[t*2+k];
    }
}

// ---------------- grouped GEMMs ----------------
#define BM 128
#define BN 128
#define BK 32
#define LDT 40   // 32 + 8 pad (80B row stride, 16B aligned, ~conflict-free)

// H[slot, f] = silu( x[token] . w1[e][f][:] )
__launch_bounds__(256)
__global__ void k_gemm1(const __bf16* __restrict__ xb, const float* __restrict__ w1,
                        const int* __restrict__ offsets, const int* __restrict__ slot_token,
                        __bf16* __restrict__ H) {
    int e = blockIdx.z;
    int base = offsets[e];
    int Me = offsets[e+1] - base;
    int m0 = blockIdx.x * BM;
    if (m0 >= Me) return;
    int n0 = blockIdx.y * BN;   // over FF

    __shared__ __bf16 As[BM][LDT];
    __shared__ __bf16 Bs[BN][LDT];

    int tid = threadIdx.x;
    int wave = tid >> 6, lane = tid & 63;
    int wm = (wave & 1) * 64, wn = (wave >> 1) * 64;

    int arow = tid >> 1, ahalf = tid & 1;       // 2 threads/row, 16 elems each
    int rloc = min(m0 + arow, Me - 1);
    int tok  = slot_token[base + rloc];
    const __bf16* aptr = xb + (size_t)tok * DD + ahalf * 16;
    const float*  bptr = w1 + ((size_t)e * FF + n0 + arow) * DD + ahalf * 16;

    f32x4 zero4 = {0.f, 0.f, 0.f, 0.f};
    f32x4 acc[4][4];
    #pragma unroll
    for (int m = 0; m < 4; m++)
        #pragma unroll
        for (int n = 0; n < 4; n++) acc[m][n] = zero4;

    for (int k0 = 0; k0 < DD; k0 += BK) {
        const bf16x8* ap = reinterpret_cast<const bf16x8*>(aptr + k0);
        bf16x8 a0 = ap[0], a1 = ap[1];
        const float4* bp = reinterpret_cast<const float4*>(bptr + k0);
        float4 q0 = bp[0], q1 = bp[1], q2 = bp[2], q3 = bp[3];
        bf16x8 b0, b1;
        b0[0]=(__bf16)q0.x; b0[1]=(__bf16)q0.y; b0[2]=(__bf16)q0.z; b0[3]=(__bf16)q0.w;
        b0[4]=(__bf16)q1.x; b0[5]=(__bf16)q1.y; b0[6]=(__bf16)q1.z; b0[7]=(__bf16)q1.w;
        b1[0]=(__bf16)q2.x; b1[1]=(__bf16)q2.y; b1[2]=(__bf16)q2.z; b1[3]=(__bf16)q2.w;
        b1[4]=(__bf16)q3.x; b1[5]=(__bf16)q3.y; b1[6]=(__bf16)q3.z; b1[7]=(__bf16)q3.w;
        *reinterpret_cast<bf16x8*>(&As[arow][ahalf*16    ]) = a0;
        *reinterpret_cast<bf16x8*>(&As[arow][ahalf*16 + 8]) = a1;
        *reinterpret_cast<bf16x8*>(&Bs[arow][ahalf*16    ]) = b0;
        *reinterpret_cast<bf16x8*>(&Bs[arow][ahalf*16 + 8]) = b1;
        __syncthreads();
        bf16x8 af[4], bfr[4];
        #pragma unroll
        for (int m = 0; m < 4; m++)
            af[m] = *reinterpret_cast<const bf16x8*>(&As[wm + m*16 + (lane & 15)][(lane >> 4) * 8]);
        #pragma unroll
        for (int n = 0; n < 4; n++)
            bfr[n] = *reinterpret_cast<const bf16x8*>(&Bs[wn + n*16 + (lane & 15)][(lane >> 4) * 8]);
        #pragma unroll
        for (int m = 0; m < 4; m++)
            #pragma unroll
            for (int n = 0; n < 4; n++)
                acc[m][n] = __builtin_amdgcn_mfma_f32_16x16x32_bf16(af[m], bfr[n], acc[m][n], 0, 0, 0);
        __syncthreads();
    }

    int rbase = wm + (lane >> 4) * 4;
    int cbase = n0 + wn + (lane & 15);
    #pragma unroll
    for (int m = 0; m < 4; m++) {
        #pragma unroll
        for (int j = 0; j < 4; j++) {
            int rl = m0 + rbase + m*16 + j;     // local row within expert group
            if (rl < Me) {
                #pragma unroll
                for (int n = 0; n < 4; n++) {
                    float v = acc[m][n][j];
                    float s = v / (1.0f + __expf(-v));     // silu
                    H[(size_t)(base + rl) * FF + cbase + n*16] = (__bf16)s;
                }
            }
        }
    }
}

// ybuf[token, kslot, d] = slot_w * ( H[slot] . w2[e][d][:] )
__launch_bounds__(256)
__global__ void k_gemm2(const __bf16* __restrict__ H, const float* __restrict__ w2,
                        const int* __restrict__ offsets,
                        const int* __restrict__ slot_token, const int* __restrict__ slot_k,
                        const float* __restrict__ slot_w,
                        float* __restrict__ ybuf) {
    int e = blockIdx.z;
    int base = offsets[e];
    int Me = offsets[e+1] - base;
    int m0 = blockIdx.x * BM;
    if (m0 >= Me) return;
    int n0 = blockIdx.y * BN;   // over DD

    __shared__ __bf16 As[BM][LDT];
    __shared__ __bf16 Bs[BN][LDT];

    int tid = threadIdx.x;
    int wave = tid >> 6, lane = tid & 63;
    int wm = (wave & 1) * 64, wn = (wave >> 1) * 64;

    int arow = tid >> 1, ahalf = tid & 1;
    int rloc = min(m0 + arow, Me - 1);
    const __bf16* aptr = H  + (size_t)(base + rloc) * FF + ahalf * 16;
    const float*  bptr = w2 + ((size_t)e * DD + n0 + arow) * FF + ahalf * 16;

    f32x4 zero4 = {0.f, 0.f, 0.f, 0.f};
    f32x4 acc[4][4];
    #pragma unroll
    for (int m = 0; m < 4; m++)
        #pragma unroll
        for (int n = 0; n < 4; n++) acc[m][n] = zero4;

    for (int k0 = 0; k0 < FF; k0 += BK) {
        const bf16x8* ap = reinterpret_cast<const bf16x8*>(aptr + k0);
        bf16x8 a0 = ap[0], a1 = ap[1];
        const float4* bp = reinterpret_cast<const float4*>(bptr + k0);
        float4 q0 = bp[0], q1 = bp[1], q2 = bp[2], q3 = bp[3];
        bf16x8 b0, b1;
        b0[0]=(__bf16)q0.x; b0[1]=(__bf16)q0.y; b0[2]=(__bf16)q0.z; b0[3]=(__bf16)q0.w;
        b0[4]=(__bf16)q1.x; b0[5]=(__bf16)q1.y; b0[6]=(__bf16)q1.z; b0[7]=(__bf16)q1.w;
        b1[0]=(__bf16)q2.x; b1[1]=(__bf16)q2.y; b1[2]=(__bf16)q2.z; b1[3]=(__bf16)q2.w;
        b1[4]=(__bf16)q3.x; b1[5]=(__bf16)q3.y; b1[6]=(__bf16)q3.z; b1[7]=(__bf16)q3.w;
        *reinterpret_cast<bf16x8*>(&As[arow][ahalf*16    ]) = a0;
        *reinterpret_cast<bf16x8*>(&As[arow][ahalf*16 + 8]) = a1;
        *reinterpret_cast<bf16x8*>(&Bs[arow][ahalf*16    ]) = b0;
        *reinterpret_cast<bf16x8*>(&Bs[arow][ahalf*16 + 8]) = b1;
        __syncthreads();
        bf16x8 af[4], bfr[4];
        #pragma unroll
        for (int m = 0; m < 4; m++)
            af[m] = *reinterpret_cast<const bf16x8*>(&As[wm + m*16 + (lane & 15)][(lane >> 4) * 8]);
        #pragma unroll
        for (int n = 0; n < 4; n++)
            bfr[n] = *reinterpret_cast<const bf16x8*>(&Bs[wn + n*16 + (lane & 15)][(lane >> 4) * 8]);
        #pragma unroll
        for (int m = 0; m < 4; m++)
            #pragma unroll
            for (int n = 0; n < 4; n++)
                acc[m][n] = __builtin_amdgcn_mfma_f32_16x16x32_bf16(af[m], bfr[n], acc[m][n], 0, 0, 0);
        __syncthreads();
    }

    int rbase = wm + (lane >> 4) * 4;
    int cb = n0 + wn + (lane & 15);
    #pragma unroll
    for (int m = 0; m < 4; m++) {
        #pragma unroll
        for (int j = 0; j < 4; j++) {
            int rl = m0 + rbase + m*16 + j;
            if (rl < Me) {
                int p = base + rl;
                int tok = slot_token[p];
                int kk  = slot_k[p];
                float wv = slot_w[p];
                float* yrow = ybuf + ((size_t)tok * 2 + kk) * DD + cb;
                #pragma unroll
                for (int n = 0; n < 4; n++) yrow[n*16] = acc[m][n][j] * wv;
            }
        }
    }
}

// out[t, d] = ybuf[t,0,d] + ybuf[t,1,d]
__global__ void k_combine(const float* __restrict__ yb, float* __restrict__ out) {
    int i = blockIdx.x * blockDim.x + threadIdx.x;   // one float4 of out
    int t = i >> 8;                                  // 256 float4 per row
    int c = i & 255;
    const f32x4* a = reinterpret_cast<const f32x4*>(yb + (size_t)t * 2 * DD);
    f32x4 va = a[c];
    f32x4 vb = a[c + 256];
    reinterpret_cast<f32x4*>(out)[i] = va + vb;
}

extern "C" void kernel_launch(void* const* d_in, const int* in_sizes, int n_in,
                              void* d_out, int out_size, void* d_ws, size_t ws_size,
                              hipStream_t stream) {
    const float* x  = (const float*)d_in[0];
    const float* rw = (const float*)d_in[1];
    const float* w1 = (const float*)d_in[2];
    const float* w2 = (const float*)d_in[3];
    const float* es = (const float*)d_in[4];
    float* out = (float*)d_out;

    uint8_t* ws = (uint8_t*)d_ws;
    __bf16* xb   = (__bf16*)ws;  ws += (size_t)NT * DD * 2;       // 4 MB
    __bf16* H    = (__bf16*)ws;  ws += (size_t)NSLOT * FF * 2;    // 32 MB
    float*  ybuf = (float*)ws;   ws += (size_t)NT * 2 * DD * 4;   // 16 MB
    int*    counts   = (int*)ws; ws += 64;
    int*    offsets  = (int*)ws; ws += 64;
    int*    tidx     = (int*)ws; ws += (size_t)NT * 2 * 4;
    float*  tw       = (float*)ws; ws += (size_t)NT * 2 * 4;
    int*    rank     = (int*)ws; ws += (size_t)NT * 2 * 4;
    int*    slot_token = (int*)ws; ws += (size_t)NSLOT * 4;
    int*    slot_k     = (int*)ws; ws += (size_t)NSLOT * 4;
    float*  slot_w     = (float*)ws; ws += (size_t)NSLOT * 4;

    hipMemsetAsync(counts, 0, NE * sizeof(int), stream);
    k_convert_x<<<NT * DD / 4 / 256, 256, 0, stream>>>(x, xb);
    k_router<<<NT, 64, 0, stream>>>(x, rw, es, counts, rank, tidx, tw);
    k_prefix<<<1, 1, 0, stream>>>(counts, offsets);
    k_scatter<<<NT / 256, 256, 0, stream>>>(tidx, tw, rank, offsets, slot_token, slot_k, slot_w);
    dim3 g1(NT / BM, FF / BN, NE);   // m-tiles innermost for B-panel L2 reuse
    k_gemm1<<<g1, 256, 0, stream>>>(xb, w1, offsets, slot_token, H);
    dim3 g2(NT / BM, DD / BN, NE);
    k_gemm2<<<g2, 256, 0, stream>>>(H, w2, offsets, slot_token, slot_k, slot_w, ybuf);
    k_combine<<<NT * DD / 4 / 256, 256, 0, stream>>>(ybuf, out);
}